// Round 3
// baseline (511.206 us; speedup 1.0000x reference)
//
#include <hip/hip_runtime.h>
#include <math.h>

// Problem constants (from setup_inputs): B=32, S=2048, Dv=Dk=A=1024, all f32.
#define B 32
#define S 2048
#define D 1024
#define CPB 32                 // block-level chunks per batch (softmax partials)
#define CHROWS (S / CPB)       // 64 rows per block
#define WROWS (CHROWS / 4)     // 16 rows per wave (4 waves/block, independent)
#define ACH 16                 // a-chunks for kq partial GEMM
#define SCALE (1.0f / 32.0f)   // 1/sqrt(A)
#define LN_EPS 1e-5f

__device__ __forceinline__ float wave_sum(float v) {
#pragma unroll
  for (int off = 32; off > 0; off >>= 1) v += __shfl_xor(v, off, 64);
  return v;
}

// ---------------------------------------------------------------------------
// Generic tiny GEMM: Y[b,r] = act(dot(X[b,0:1024], W[r,0:1024])), b<32, r<1024.
// tid -> b = tid&31, r = tid>>5: W row address uniform per 32-lane group
// (broadcast + L1 reuse), W streamed from HBM exactly once (4 MB).
// block=128 -> 256 blocks -> one per CU (latency-bound kernel; spread wide).
__global__ __launch_bounds__(128) void gemm_xw(const float* __restrict__ X,
                                               const float* __restrict__ W,
                                               float* __restrict__ Y,
                                               const int do_tanh) {
  const int tid = blockIdx.x * 128 + threadIdx.x;
  const int b = tid & (B - 1);
  const int r = tid >> 5;
  const float4* x4 = (const float4*)(X + (size_t)b * D);
  const float4* w4 = (const float4*)(W + (size_t)r * D);
  float acc = 0.f;
#pragma unroll 8
  for (int k = 0; k < D / 4; ++k) {
    float4 a = x4[k];
    float4 w = w4[k];
    acc += a.x * w.x + a.y * w.y + a.z * w.z + a.w * w.w;
  }
  if (do_tanh) acc = tanhf(acc);
  Y[(size_t)b * D + r] = acc;
}

// ---------------------------------------------------------------------------
// kq[b,d] = sum_a q[b,a] * WK[a,d]  (row-coalesced WK stream).
// Partials over a-chunks for parallelism without atomics. kqp: [ACH][B][D]
__global__ __launch_bounds__(256) void kq_partial(const float* __restrict__ q,
                                                  const float* __restrict__ WK,
                                                  float* __restrict__ kqp) {
  const int t = threadIdx.x, ac = blockIdx.x, bg = blockIdx.y;  // bg in [0,4)
  const int d0 = t * 4;
  float accx[8] = {}, accy[8] = {}, accz[8] = {}, accw[8] = {};
  const int a0 = ac * (1024 / ACH);
  for (int a = a0; a < a0 + (1024 / ACH); ++a) {
    float4 wk = *(const float4*)(WK + (size_t)a * D + d0);  // coalesced row
#pragma unroll
    for (int j = 0; j < 8; ++j) {
      float qv = q[(size_t)(bg * 8 + j) * D + a];  // broadcast
      accx[j] += qv * wk.x;
      accy[j] += qv * wk.y;
      accz[j] += qv * wk.z;
      accw[j] += qv * wk.w;
    }
  }
#pragma unroll
  for (int j = 0; j < 8; ++j) {
    float4 o;
    o.x = accx[j]; o.y = accy[j]; o.z = accz[j]; o.w = accw[j];
    *(float4*)(kqp + ((size_t)ac * B + bg * 8 + j) * D + d0) = o;
  }
}

__global__ __launch_bounds__(256) void kq_reduce(const float* __restrict__ kqp,
                                                 float* __restrict__ kq) {
  const int i4 = (blockIdx.x * 256 + threadIdx.x) * 4;  // grid = 32 blocks
  float sx = 0.f, sy = 0.f, sz = 0.f, sw = 0.f;
  for (int c = 0; c < ACH; ++c) {
    float4 v = *(const float4*)(kqp + (size_t)c * (B * D) + i4);
    sx += v.x; sy += v.y; sz += v.z; sw += v.w;
  }
  float4 o;
  o.x = sx; o.y = sy; o.z = sz; o.w = sw;
  *(float4*)(kq + i4) = o;
}

// ---------------------------------------------------------------------------
// Main pass v2: single streaming read of meta (268 MB), ZERO barriers in the
// stream loop. Each wave owns WROWS=16 full rows: per row it loads 4 KB
// (4x float4/lane), computes the logit with a pure in-wave shuffle reduce,
// and maintains a private online-softmax state (m, l, acc[4] float4).
// One LDS reduce per block at the end merges the 4 waves -> chunk partial.
__global__ __launch_bounds__(256) void attn_main(
    const float* __restrict__ meta, const float* __restrict__ kq,
    float* __restrict__ logits_out, float* __restrict__ cm,
    float* __restrict__ cl, float* __restrict__ cacc) {
  const int c = blockIdx.x, b = blockIdx.y;
  const int t = threadIdx.x, w = t >> 6, lane = t & 63;
  const int row0 = c * CHROWS + w * WROWS;
  const float* base = meta + ((size_t)b * S + row0) * D + lane * 4;

  // kq fragment: lane covers d = lane*4 + j*256, j=0..3
  float4 kqf[4];
#pragma unroll
  for (int j = 0; j < 4; ++j)
    kqf[j] = *(const float4*)(kq + (size_t)b * D + j * 256 + lane * 4);

  float4 acc[4] = {};
  float m = -INFINITY, l = 0.f;

  float4 v[4], vn[4];
#pragma unroll
  for (int j = 0; j < 4; ++j) v[j] = *(const float4*)(base + j * 256);

  for (int s = 0; s < WROWS; ++s) {
    // prefetch next row before the reduce chain (stays in flight; no barrier)
    const float* nb = base + (size_t)(s + 1 < WROWS ? s + 1 : s) * D;
#pragma unroll
    for (int j = 0; j < 4; ++j) vn[j] = *(const float4*)(nb + j * 256);

    float p = 0.f;
#pragma unroll
    for (int j = 0; j < 4; ++j)
      p += v[j].x * kqf[j].x + v[j].y * kqf[j].y + v[j].z * kqf[j].z +
           v[j].w * kqf[j].w;
    p = wave_sum(p);
    const float logit = p * SCALE;
    if (lane == 0) logits_out[(size_t)b * S + row0 + s] = logit;

    if (logit > m) {  // wave-uniform; ~H(16)~=3.4 hits per wave on random data
      const float f = expf(m - logit);  // expf(-inf)=0 handles first row
#pragma unroll
      for (int j = 0; j < 4; ++j) {
        acc[j].x *= f; acc[j].y *= f; acc[j].z *= f; acc[j].w *= f;
      }
      l *= f;
      m = logit;
    }
    const float p2 = expf(logit - m);
#pragma unroll
    for (int j = 0; j < 4; ++j) {
      acc[j].x += p2 * v[j].x; acc[j].y += p2 * v[j].y;
      acc[j].z += p2 * v[j].z; acc[j].w += p2 * v[j].w;
    }
    l += p2;
#pragma unroll
    for (int j = 0; j < 4; ++j) v[j] = vn[j];
  }

  // merge the 4 waves' partials (one barrier per block, not per row)
  __shared__ float lds_acc[4][D];  // 16 KB
  __shared__ float lds_m[4], lds_l[4];
  if (lane == 0) { lds_m[w] = m; lds_l[w] = l; }
#pragma unroll
  for (int j = 0; j < 4; ++j)
    *(float4*)(&lds_acc[w][j * 256 + lane * 4]) = acc[j];
  __syncthreads();

  const float M = fmaxf(fmaxf(lds_m[0], lds_m[1]), fmaxf(lds_m[2], lds_m[3]));
  float fac[4], L = 0.f;
#pragma unroll
  for (int w2 = 0; w2 < 4; ++w2) {
    fac[w2] = expf(lds_m[w2] - M);
    L += lds_l[w2] * fac[w2];
  }
  float4 sv = {};
#pragma unroll
  for (int w2 = 0; w2 < 4; ++w2) {
    float4 a = *(const float4*)(&lds_acc[w2][t * 4]);
    sv.x += fac[w2] * a.x; sv.y += fac[w2] * a.y;
    sv.z += fac[w2] * a.z; sv.w += fac[w2] * a.w;
  }
  const int pc = b * CPB + c;
  *(float4*)(cacc + (size_t)pc * D + t * 4) = sv;
  if (t == 0) { cm[pc] = M; cl[pc] = L; }
}

// ---------------------------------------------------------------------------
// Combine chunk partials: global M, L; wm[b,d] = (sum_c f_c*acc_c[d]) / L;
// finalize weight output in place: w = exp(logit - M) / L.
__global__ __launch_bounds__(256) void combine(const float* __restrict__ cm,
                                               const float* __restrict__ cl,
                                               const float* __restrict__ cacc,
                                               float* __restrict__ wio,
                                               float* __restrict__ wm) {
  const int b = blockIdx.x, t = threadIdx.x;
  float M = -INFINITY;
  for (int c2 = 0; c2 < CPB; ++c2) M = fmaxf(M, cm[b * CPB + c2]);
  float L = 0.f;
  for (int c2 = 0; c2 < CPB; ++c2) L += cl[b * CPB + c2] * expf(cm[b * CPB + c2] - M);
  const float invL = 1.0f / L;

  float sx = 0.f, sy = 0.f, sz = 0.f, sw = 0.f;
  for (int c2 = 0; c2 < CPB; ++c2) {
    const float f = expf(cm[b * CPB + c2] - M);
    float4 a = *(const float4*)(cacc + ((size_t)b * CPB + c2) * D + 4 * t);
    sx += f * a.x; sy += f * a.y; sz += f * a.z; sw += f * a.w;
  }
  float4 o;
  o.x = sx * invL; o.y = sy * invL; o.z = sz * invL; o.w = sw * invL;
  *(float4*)(wm + (size_t)b * D + 4 * t) = o;

  for (int s = t; s < S; s += 256) {
    const float lg = wio[(size_t)b * S + s];
    wio[(size_t)b * S + s] = expf(lg - M) * invL;
  }
}

// ---------------------------------------------------------------------------
// LayerNorm over last dim per b; out = (h-mu)/sqrt(var+eps)*w + b.
__global__ __launch_bounds__(256) void ln_kernel(const float* __restrict__ h,
                                                 const float* __restrict__ lnw,
                                                 const float* __restrict__ lnb,
                                                 float* __restrict__ out) {
  const int b = blockIdx.x, t = threadIdx.x, wid = t >> 6, lane = t & 63;
  __shared__ float r1[4], r2[4];
  float4 v = *(const float4*)(h + (size_t)b * D + 4 * t);
  float s1 = v.x + v.y + v.z + v.w;
  float s2 = v.x * v.x + v.y * v.y + v.z * v.z + v.w * v.w;
  s1 = wave_sum(s1);
  s2 = wave_sum(s2);
  if (lane == 0) { r1[wid] = s1; r2[wid] = s2; }
  __syncthreads();
  const float mean = (r1[0] + r1[1] + r1[2] + r1[3]) * (1.0f / D);
  const float ms = (r2[0] + r2[1] + r2[2] + r2[3]) * (1.0f / D);
  const float var = ms - mean * mean;
  const float rstd = rsqrtf(var + LN_EPS);
  float4 w = *(const float4*)(lnw + 4 * t);
  float4 bb = *(const float4*)(lnb + 4 * t);
  float4 o;
  o.x = (v.x - mean) * rstd * w.x + bb.x;
  o.y = (v.y - mean) * rstd * w.y + bb.y;
  o.z = (v.z - mean) * rstd * w.z + bb.z;
  o.w = (v.w - mean) * rstd * w.w + bb.w;
  *(float4*)(out + (size_t)b * D + 4 * t) = o;
}

// ---------------------------------------------------------------------------
extern "C" void kernel_launch(void* const* d_in, const int* in_sizes, int n_in,
                              void* d_out, int out_size, void* d_ws,
                              size_t ws_size, hipStream_t stream) {
  (void)in_sizes; (void)n_in; (void)out_size; (void)ws_size;
  const float* meta   = (const float*)d_in[0];
  const float* hidden = (const float*)d_in[1];
  const float* WK = (const float*)d_in[2];
  const float* WQ = (const float*)d_in[3];
  const float* WV = (const float*)d_in[4];
  const float* WO = (const float*)d_in[5];
  const float* lnw = (const float*)d_in[6];
  const float* lnb = (const float*)d_in[7];

  float* out  = (float*)d_out;        // [B, D] LayerNorm output
  float* wout = out + B * D;          // [B, S] softmax weights (logits first)

  // workspace layout (floats); total ~1.74M floats ~= 7 MB
  float* ws   = (float*)d_ws;
  float* q    = ws;                         // B*D
  float* kqp  = q + B * D;                  // ACH*B*D
  float* kq   = kqp + (size_t)ACH * B * D;  // B*D
  float* cm   = kq + B * D;                 // B*CPB
  float* cl   = cm + B * CPB;               // B*CPB
  float* cacc = cl + B * CPB;               // B*CPB*D
  float* wm   = cacc + (size_t)B * CPB * D; // B*D
  float* att  = wm + B * D;                 // B*D
  float* h    = att + B * D;                // B*D

  // q = hidden @ WQ^T
  gemm_xw<<<dim3((B * D) / 128), 128, 0, stream>>>(hidden, WQ, q, 0);
  // kq = q @ WK (via partials over a-chunks)
  kq_partial<<<dim3(ACH, 4), 256, 0, stream>>>(q, WK, kqp);
  kq_reduce<<<dim3((B * D) / 1024), 256, 0, stream>>>(kqp, kq);
  // single pass over meta: logits + online-softmax weighted-meta partials
  attn_main<<<dim3(CPB, B), 256, 0, stream>>>(meta, kq, wout, cm, cl, cacc);
  // combine partials -> wm, finalize weights in d_out
  combine<<<dim3(B), 256, 0, stream>>>(cm, cl, cacc, wout, wm);
  // attention = wm @ WV^T ; h = tanh(attention @ WO^T) ; out = LN(h)
  gemm_xw<<<dim3((B * D) / 128), 128, 0, stream>>>(wm, WV, att, 0);
  gemm_xw<<<dim3((B * D) / 128), 128, 0, stream>>>(att, WO, h, 1);
  ln_kernel<<<dim3(B), 256, 0, stream>>>(h, lnw, lnb, out);
}

// Round 4
// 475.591 us; speedup vs baseline: 1.0749x; 1.0749x over previous
//
#include <hip/hip_runtime.h>
#include <math.h>

// Problem constants (from setup_inputs): B=32, S=2048, Dv=Dk=A=1024, all f32.
#define B 32
#define S 2048
#define D 1024
#define CPB 64                 // block-level chunks per batch (softmax partials)
#define CHROWS (S / CPB)       // 32 rows per block
#define WROWS (CHROWS / 4)     // 8 rows per wave (4 waves/block, independent)
#define ACH 16                 // a-chunks for kq partial GEMM
#define SCALE (1.0f / 32.0f)   // 1/sqrt(A)
#define LN_EPS 1e-5f

__device__ __forceinline__ float wave_sum(float v) {
#pragma unroll
  for (int off = 32; off > 0; off >>= 1) v += __shfl_xor(v, off, 64);
  return v;
}

// ---------------------------------------------------------------------------
// Tiny GEMV bank: Y[b,r] = act(dot(X[b,:], W[r,:])), b<32, r<1024.
// Grid 256 blocks x 256 thr: block owns 4 r-values; K split in halves across
// thread groups (kh), combined via LDS. One block per CU, 4 waves each.
// W streamed from HBM exactly once; X (128 KB) is L2-hot gather.
__global__ __launch_bounds__(256) void gemm_xw(const float* __restrict__ X,
                                               const float* __restrict__ W,
                                               float* __restrict__ Y,
                                               const int do_tanh) {
  const int t = threadIdx.x;
  const int b = t & 31;
  const int rr = (t >> 5) & 3;
  const int kh = t >> 7;  // 0/1: K-half
  const int r = blockIdx.x * 4 + rr;
  const float4* x4 = (const float4*)(X + (size_t)b * D + kh * (D / 2));
  const float4* w4 = (const float4*)(W + (size_t)r * D + kh * (D / 2));
  float acc = 0.f;
#pragma unroll 8
  for (int k = 0; k < D / 8; ++k) {  // 128 float4 pairs per thread
    float4 a = x4[k];
    float4 w = w4[k];
    acc += a.x * w.x + a.y * w.y + a.z * w.z + a.w * w.w;
  }
  __shared__ float part[256];
  part[t] = acc;
  __syncthreads();
  if (kh == 0) {
    float v = part[t] + part[t + 128];
    if (do_tanh) v = tanhf(v);
    Y[(size_t)b * D + r] = v;
  }
}

// ---------------------------------------------------------------------------
// kq[b,d] = sum_a q[b,a] * WK[a,d]  (row-coalesced WK stream).
// Partials over a-chunks for parallelism without atomics. kqp: [ACH][B][D]
__global__ __launch_bounds__(256) void kq_partial(const float* __restrict__ q,
                                                  const float* __restrict__ WK,
                                                  float* __restrict__ kqp) {
  const int t = threadIdx.x, ac = blockIdx.x, bg = blockIdx.y;  // bg in [0,4)
  const int d0 = t * 4;
  float accx[8] = {}, accy[8] = {}, accz[8] = {}, accw[8] = {};
  const int a0 = ac * (1024 / ACH);
  for (int a = a0; a < a0 + (1024 / ACH); ++a) {
    float4 wk = *(const float4*)(WK + (size_t)a * D + d0);  // coalesced row
#pragma unroll
    for (int j = 0; j < 8; ++j) {
      float qv = q[(size_t)(bg * 8 + j) * D + a];  // broadcast
      accx[j] += qv * wk.x;
      accy[j] += qv * wk.y;
      accz[j] += qv * wk.z;
      accw[j] += qv * wk.w;
    }
  }
#pragma unroll
  for (int j = 0; j < 8; ++j) {
    float4 o;
    o.x = accx[j]; o.y = accy[j]; o.z = accz[j]; o.w = accw[j];
    *(float4*)(kqp + ((size_t)ac * B + bg * 8 + j) * D + d0) = o;
  }
}

__global__ __launch_bounds__(64) void kq_reduce(const float* __restrict__ kqp,
                                                float* __restrict__ kq) {
  const int i4 = (blockIdx.x * 64 + threadIdx.x) * 4;  // 128 blocks x 64 thr
  float sx = 0.f, sy = 0.f, sz = 0.f, sw = 0.f;
  for (int c = 0; c < ACH; ++c) {
    float4 v = *(const float4*)(kqp + (size_t)c * (B * D) + i4);
    sx += v.x; sy += v.y; sz += v.z; sw += v.w;
  }
  float4 o;
  o.x = sx; o.y = sy; o.z = sz; o.w = sw;
  *(float4*)(kq + i4) = o;
}

// ---------------------------------------------------------------------------
// Main pass: single streaming read of meta (268 MB), ZERO barriers in the
// stream loop. Each wave owns WROWS=8 full rows: per row it loads 4 KB
// (4x float4/lane), computes the logit with a pure in-wave shuffle reduce,
// and maintains a private online-softmax state (m, l, acc[4] float4).
// One LDS reduce per block at the end merges the 4 waves -> chunk partial.
// Grid 64x32 = 2048 blocks -> ~8 blocks/CU for HBM saturation.
__global__ __launch_bounds__(256) void attn_main(
    const float* __restrict__ meta, const float* __restrict__ kq,
    float* __restrict__ logits_out, float* __restrict__ cm,
    float* __restrict__ cl, float* __restrict__ cacc) {
  const int c = blockIdx.x, b = blockIdx.y;
  const int t = threadIdx.x, w = t >> 6, lane = t & 63;
  const int row0 = c * CHROWS + w * WROWS;
  const float* base = meta + ((size_t)b * S + row0) * D + lane * 4;

  // kq fragment: lane covers d = lane*4 + j*256, j=0..3
  float4 kqf[4];
#pragma unroll
  for (int j = 0; j < 4; ++j)
    kqf[j] = *(const float4*)(kq + (size_t)b * D + j * 256 + lane * 4);

  float4 acc[4] = {};
  float m = -INFINITY, l = 0.f;

  float4 v[4], vn[4];
#pragma unroll
  for (int j = 0; j < 4; ++j) v[j] = *(const float4*)(base + j * 256);

  for (int s = 0; s < WROWS; ++s) {
    // prefetch next row before the reduce chain (stays in flight; no barrier)
    const float* nb = base + (size_t)(s + 1 < WROWS ? s + 1 : s) * D;
#pragma unroll
    for (int j = 0; j < 4; ++j) vn[j] = *(const float4*)(nb + j * 256);

    float p = 0.f;
#pragma unroll
    for (int j = 0; j < 4; ++j)
      p += v[j].x * kqf[j].x + v[j].y * kqf[j].y + v[j].z * kqf[j].z +
           v[j].w * kqf[j].w;
    p = wave_sum(p);
    const float logit = p * SCALE;
    if (lane == 0) logits_out[(size_t)b * S + row0 + s] = logit;

    if (logit > m) {  // wave-uniform; ~H(8)~=2.7 hits per wave on random data
      const float f = expf(m - logit);  // expf(-inf)=0 handles first row
#pragma unroll
      for (int j = 0; j < 4; ++j) {
        acc[j].x *= f; acc[j].y *= f; acc[j].z *= f; acc[j].w *= f;
      }
      l *= f;
      m = logit;
    }
    const float p2 = expf(logit - m);
#pragma unroll
    for (int j = 0; j < 4; ++j) {
      acc[j].x += p2 * v[j].x; acc[j].y += p2 * v[j].y;
      acc[j].z += p2 * v[j].z; acc[j].w += p2 * v[j].w;
    }
    l += p2;
#pragma unroll
    for (int j = 0; j < 4; ++j) v[j] = vn[j];
  }

  // merge the 4 waves' partials (one barrier per block, not per row)
  __shared__ float lds_acc[4][D];  // 16 KB
  __shared__ float lds_m[4], lds_l[4];
  if (lane == 0) { lds_m[w] = m; lds_l[w] = l; }
#pragma unroll
  for (int j = 0; j < 4; ++j)
    *(float4*)(&lds_acc[w][j * 256 + lane * 4]) = acc[j];
  __syncthreads();

  const float M = fmaxf(fmaxf(lds_m[0], lds_m[1]), fmaxf(lds_m[2], lds_m[3]));
  float fac[4], L = 0.f;
#pragma unroll
  for (int w2 = 0; w2 < 4; ++w2) {
    fac[w2] = expf(lds_m[w2] - M);
    L += lds_l[w2] * fac[w2];
  }
  float4 sv = {};
#pragma unroll
  for (int w2 = 0; w2 < 4; ++w2) {
    float4 a = *(const float4*)(&lds_acc[w2][t * 4]);
    sv.x += fac[w2] * a.x; sv.y += fac[w2] * a.y;
    sv.z += fac[w2] * a.z; sv.w += fac[w2] * a.w;
  }
  const int pc = b * CPB + c;
  *(float4*)(cacc + (size_t)pc * D + t * 4) = sv;
  if (t == 0) { cm[pc] = M; cl[pc] = L; }
}

// ---------------------------------------------------------------------------
// Combine chunk partials. Grid (32 b, 8 dtile) x 128 thr so the 8 MB cacc
// reduction spreads over 256 blocks. Block (b,dt): wm for d in
// [dt*128, dt*128+128) and weight finalization for s in [dt*256, dt*256+256).
__global__ __launch_bounds__(128) void combine(const float* __restrict__ cm,
                                               const float* __restrict__ cl,
                                               const float* __restrict__ cacc,
                                               float* __restrict__ wio,
                                               float* __restrict__ wm) {
  const int b = blockIdx.x, dt = blockIdx.y, t = threadIdx.x;
  float M = -INFINITY;
  for (int c2 = 0; c2 < CPB; ++c2) M = fmaxf(M, cm[b * CPB + c2]);
  __shared__ float fac[CPB];
  if (t < CPB) fac[t] = expf(cm[b * CPB + t] - M);
  __syncthreads();
  float L = 0.f;
  for (int c2 = 0; c2 < CPB; ++c2) L += cl[b * CPB + c2] * fac[c2];
  const float invL = 1.0f / L;

  const int d = dt * 128 + t;
  float sv = 0.f;
  for (int c2 = 0; c2 < CPB; ++c2)
    sv += fac[c2] * cacc[((size_t)b * CPB + c2) * D + d];
  wm[(size_t)b * D + d] = sv * invL;

  for (int s = dt * 256 + t; s < dt * 256 + 256; s += 128) {
    const float lg = wio[(size_t)b * S + s];
    wio[(size_t)b * S + s] = expf(lg - M) * invL;
  }
}

// ---------------------------------------------------------------------------
// LayerNorm over last dim per b; out = (h-mu)/sqrt(var+eps)*w + b.
__global__ __launch_bounds__(256) void ln_kernel(const float* __restrict__ h,
                                                 const float* __restrict__ lnw,
                                                 const float* __restrict__ lnb,
                                                 float* __restrict__ out) {
  const int b = blockIdx.x, t = threadIdx.x, wid = t >> 6, lane = t & 63;
  __shared__ float r1[4], r2[4];
  float4 v = *(const float4*)(h + (size_t)b * D + 4 * t);
  float s1 = v.x + v.y + v.z + v.w;
  float s2 = v.x * v.x + v.y * v.y + v.z * v.z + v.w * v.w;
  s1 = wave_sum(s1);
  s2 = wave_sum(s2);
  if (lane == 0) { r1[wid] = s1; r2[wid] = s2; }
  __syncthreads();
  const float mean = (r1[0] + r1[1] + r1[2] + r1[3]) * (1.0f / D);
  const float ms = (r2[0] + r2[1] + r2[2] + r2[3]) * (1.0f / D);
  const float var = ms - mean * mean;
  const float rstd = rsqrtf(var + LN_EPS);
  float4 w = *(const float4*)(lnw + 4 * t);
  float4 bb = *(const float4*)(lnb + 4 * t);
  float4 o;
  o.x = (v.x - mean) * rstd * w.x + bb.x;
  o.y = (v.y - mean) * rstd * w.y + bb.y;
  o.z = (v.z - mean) * rstd * w.z + bb.z;
  o.w = (v.w - mean) * rstd * w.w + bb.w;
  *(float4*)(out + (size_t)b * D + 4 * t) = o;
}

// ---------------------------------------------------------------------------
extern "C" void kernel_launch(void* const* d_in, const int* in_sizes, int n_in,
                              void* d_out, int out_size, void* d_ws,
                              size_t ws_size, hipStream_t stream) {
  (void)in_sizes; (void)n_in; (void)out_size; (void)ws_size;
  const float* meta   = (const float*)d_in[0];
  const float* hidden = (const float*)d_in[1];
  const float* WK = (const float*)d_in[2];
  const float* WQ = (const float*)d_in[3];
  const float* WV = (const float*)d_in[4];
  const float* WO = (const float*)d_in[5];
  const float* lnw = (const float*)d_in[6];
  const float* lnb = (const float*)d_in[7];

  float* out  = (float*)d_out;        // [B, D] LayerNorm output
  float* wout = out + B * D;          // [B, S] softmax weights (logits first)

  // workspace layout (floats); total ~2.8M floats ~= 11 MB
  float* ws   = (float*)d_ws;
  float* q    = ws;                         // B*D
  float* kqp  = q + B * D;                  // ACH*B*D
  float* kq   = kqp + (size_t)ACH * B * D;  // B*D
  float* cm   = kq + B * D;                 // B*CPB
  float* cl   = cm + B * CPB;               // B*CPB
  float* cacc = cl + B * CPB;               // B*CPB*D
  float* wm   = cacc + (size_t)B * CPB * D; // B*D
  float* att  = wm + B * D;                 // B*D
  float* h    = att + B * D;                // B*D

  // q = hidden @ WQ^T
  gemm_xw<<<dim3(D / 4), 256, 0, stream>>>(hidden, WQ, q, 0);
  // kq = q @ WK (via partials over a-chunks)
  kq_partial<<<dim3(ACH, 4), 256, 0, stream>>>(q, WK, kqp);
  kq_reduce<<<dim3((B * D) / 256), 64, 0, stream>>>(kqp, kq);
  // single pass over meta: logits + online-softmax weighted-meta partials
  attn_main<<<dim3(CPB, B), 256, 0, stream>>>(meta, kq, wout, cm, cl, cacc);
  // combine partials -> wm, finalize weights in d_out
  combine<<<dim3(B, 8), 128, 0, stream>>>(cm, cl, cacc, wout, wm);
  // attention = wm @ WV^T ; h = tanh(attention @ WO^T) ; out = LN(h)
  gemm_xw<<<dim3(D / 4), 256, 0, stream>>>(wm, WV, att, 0);
  gemm_xw<<<dim3(D / 4), 256, 0, stream>>>(att, WO, h, 1);
  ln_kernel<<<dim3(B), 256, 0, stream>>>(h, lnw, lnb, out);
}

// Round 5
// 462.590 us; speedup vs baseline: 1.1051x; 1.0281x over previous
//
#include <hip/hip_runtime.h>
#include <math.h>

// Problem constants (from setup_inputs): B=32, S=2048, Dv=Dk=A=1024, all f32.
#define B 32
#define S 2048
#define D 1024
#define CPB 64                 // block-level chunks per batch (softmax partials)
#define CHROWS (S / CPB)       // 32 rows per block
#define WROWS (CHROWS / 4)     // 8 rows per wave (4 waves/block, independent)
#define ACH 16                 // a-chunks for kq partial GEMM
#define SCALE (1.0f / 32.0f)   // 1/sqrt(A)
#define LN_EPS 1e-5f

__device__ __forceinline__ float wave_sum(float v) {
#pragma unroll
  for (int off = 32; off > 0; off >>= 1) v += __shfl_xor(v, off, 64);
  return v;
}

__device__ __forceinline__ void wave_sum2(float& a, float& b) {
#pragma unroll
  for (int off = 32; off > 0; off >>= 1) {
    a += __shfl_xor(a, off, 64);
    b += __shfl_xor(b, off, 64);
  }
}

// ---------------------------------------------------------------------------
// GEMV bank v3: Y[b,r] = act(dot(X[b,:], W[r,:])), fully coalesced.
// Grid (8 bg, 32 rg) x 256 thr = 4 waves. Wave w owns b = bg*4+w; its X row
// lives in 16 VGPRs (loaded once, coalesced 64-lane float4). Loop r over 32
// rows of W (coalesced stream, L1-dedup across the 4 waves), software-
// pipelined next-row prefetch; in-wave shuffle reduce per output.
__global__ __launch_bounds__(256) void gemm_xw(const float* __restrict__ X,
                                               const float* __restrict__ W,
                                               float* __restrict__ Y,
                                               const int do_tanh) {
  const int w = threadIdx.x >> 6, lane = threadIdx.x & 63;
  const int b = blockIdx.x * 4 + w;
  const int r0 = blockIdx.y * 32;

  float4 x[4];
  const float4* xrow = (const float4*)(X + (size_t)b * D) + lane;
#pragma unroll
  for (int j = 0; j < 4; ++j) x[j] = xrow[j * 64];

  float4 wv[4], wn[4];
  const float4* wrow = (const float4*)(W + (size_t)r0 * D) + lane;
#pragma unroll
  for (int j = 0; j < 4; ++j) wv[j] = wrow[j * 64];

  for (int i = 0; i < 32; ++i) {
    const float4* wnext =
        (const float4*)(W + (size_t)(r0 + (i + 1 < 32 ? i + 1 : i)) * D) + lane;
#pragma unroll
    for (int j = 0; j < 4; ++j) wn[j] = wnext[j * 64];

    float p = 0.f;
#pragma unroll
    for (int j = 0; j < 4; ++j)
      p += x[j].x * wv[j].x + x[j].y * wv[j].y + x[j].z * wv[j].z +
           x[j].w * wv[j].w;
    p = wave_sum(p);
    if (lane == 0) {
      if (do_tanh) p = tanhf(p);
      Y[(size_t)b * D + r0 + i] = p;
    }
#pragma unroll
    for (int j = 0; j < 4; ++j) wv[j] = wn[j];
  }
}

// ---------------------------------------------------------------------------
// kq partials: kqp[ac][b][d] = sum_{a in chunk ac} q[b,a] * WK[a,d].
// Row-coalesced WK stream; q scalar broadcast. Final reduction over ac is
// fused into attn_main (kqp stays L2-resident, 2 MB).
__global__ __launch_bounds__(256) void kq_partial(const float* __restrict__ q,
                                                  const float* __restrict__ WK,
                                                  float* __restrict__ kqp) {
  const int t = threadIdx.x, ac = blockIdx.x, bg = blockIdx.y;  // bg in [0,4)
  const int d0 = t * 4;
  float accx[8] = {}, accy[8] = {}, accz[8] = {}, accw[8] = {};
  const int a0 = ac * (1024 / ACH);
  for (int a = a0; a < a0 + (1024 / ACH); ++a) {
    float4 wk = *(const float4*)(WK + (size_t)a * D + d0);  // coalesced row
#pragma unroll
    for (int j = 0; j < 8; ++j) {
      float qv = q[(size_t)(bg * 8 + j) * D + a];  // broadcast
      accx[j] += qv * wk.x;
      accy[j] += qv * wk.y;
      accz[j] += qv * wk.z;
      accw[j] += qv * wk.w;
    }
  }
#pragma unroll
  for (int j = 0; j < 8; ++j) {
    float4 o;
    o.x = accx[j]; o.y = accy[j]; o.z = accz[j]; o.w = accw[j];
    *(float4*)(kqp + ((size_t)ac * B + bg * 8 + j) * D + d0) = o;
  }
}

// ---------------------------------------------------------------------------
// Main pass: single streaming read of meta (268 MB), ZERO barriers in the
// stream loop. Start: block reduces kqp -> kq row in LDS (once, L2-hot).
// Each wave owns 8 rows, processed 2 at a time (two independent shuffle-
// reduce chains for ILP, 8 KB load-ahead). Private online-softmax state;
// one LDS merge per block at the end.
__global__ __launch_bounds__(256) void attn_main(
    const float* __restrict__ meta, const float* __restrict__ kqp,
    float* __restrict__ logits_out, float* __restrict__ cm,
    float* __restrict__ cl, float* __restrict__ cacc) {
  const int c = blockIdx.x, b = blockIdx.y;
  const int t = threadIdx.x, w = t >> 6, lane = t & 63;
  const int row0 = c * CHROWS + w * WROWS;
  const float* base = meta + ((size_t)b * S + row0) * D + lane * 4;

  __shared__ float lds_acc[4][D];  // 16 KB; lds_acc[0] doubles as kq row
  __shared__ float lds_m[4], lds_l[4];
  float* kq_lds = &lds_acc[0][0];

  // --- fused kq reduction: thread t owns d = [4t, 4t+4) ---
  {
    float sx = 0.f, sy = 0.f, sz = 0.f, sw = 0.f;
#pragma unroll
    for (int ch = 0; ch < ACH; ++ch) {
      float4 kv = *(const float4*)(kqp + ((size_t)ch * B + b) * D + 4 * t);
      sx += kv.x; sy += kv.y; sz += kv.z; sw += kv.w;
    }
    float4 o;
    o.x = sx; o.y = sy; o.z = sz; o.w = sw;
    *(float4*)(&kq_lds[4 * t]) = o;
  }

  // preload rows 0,1 (independent of LDS)
  float4 v0[4], v1[4];
#pragma unroll
  for (int j = 0; j < 4; ++j) {
    v0[j] = *(const float4*)(base + j * 256);
    v1[j] = *(const float4*)(base + D + j * 256);
  }

  __syncthreads();  // kq_lds ready
  float4 kqf[4];
#pragma unroll
  for (int j = 0; j < 4; ++j)
    kqf[j] = *(const float4*)(&kq_lds[j * 256 + lane * 4]);
  __syncthreads();  // all kq_lds reads done before lds_acc reuse

  float4 acc[4] = {};
  float m = -INFINITY, l = 0.f;

  for (int it = 0; it < WROWS / 2; ++it) {
    // prefetch next row pair (clamped; redundant loads hit L1)
    const int nr = (it + 1 < WROWS / 2) ? 2 * it + 2 : 2 * it;
    const float* nb = base + (size_t)nr * D;
    float4 n0[4], n1[4];
#pragma unroll
    for (int j = 0; j < 4; ++j) {
      n0[j] = *(const float4*)(nb + j * 256);
      n1[j] = *(const float4*)(nb + D + j * 256);
    }

    float pa = 0.f, pb = 0.f;
#pragma unroll
    for (int j = 0; j < 4; ++j) {
      pa += v0[j].x * kqf[j].x + v0[j].y * kqf[j].y + v0[j].z * kqf[j].z +
            v0[j].w * kqf[j].w;
      pb += v1[j].x * kqf[j].x + v1[j].y * kqf[j].y + v1[j].z * kqf[j].z +
            v1[j].w * kqf[j].w;
    }
    wave_sum2(pa, pb);
    const float la = pa * SCALE, lb = pb * SCALE;
    if (lane == 0) {
      logits_out[(size_t)b * S + row0 + 2 * it] = la;
      logits_out[(size_t)b * S + row0 + 2 * it + 1] = lb;
    }

    const float mn = fmaxf(m, fmaxf(la, lb));
    if (mn > m) {  // wave-uniform rescale; first iter: __expf(-inf)=0
      const float f = __expf(m - mn);
#pragma unroll
      for (int j = 0; j < 4; ++j) {
        acc[j].x *= f; acc[j].y *= f; acc[j].z *= f; acc[j].w *= f;
      }
      l *= f;
      m = mn;
    }
    const float ea = __expf(la - m), eb = __expf(lb - m);
#pragma unroll
    for (int j = 0; j < 4; ++j) {
      acc[j].x += ea * v0[j].x + eb * v1[j].x;
      acc[j].y += ea * v0[j].y + eb * v1[j].y;
      acc[j].z += ea * v0[j].z + eb * v1[j].z;
      acc[j].w += ea * v0[j].w + eb * v1[j].w;
    }
    l += ea + eb;
#pragma unroll
    for (int j = 0; j < 4; ++j) { v0[j] = n0[j]; v1[j] = n1[j]; }
  }

  // merge the 4 waves' partials (one barrier per block, not per row)
  if (lane == 0) { lds_m[w] = m; lds_l[w] = l; }
#pragma unroll
  for (int j = 0; j < 4; ++j)
    *(float4*)(&lds_acc[w][j * 256 + lane * 4]) = acc[j];
  __syncthreads();

  const float M = fmaxf(fmaxf(lds_m[0], lds_m[1]), fmaxf(lds_m[2], lds_m[3]));
  float fac[4], L = 0.f;
#pragma unroll
  for (int w2 = 0; w2 < 4; ++w2) {
    fac[w2] = __expf(lds_m[w2] - M);
    L += lds_l[w2] * fac[w2];
  }
  float4 sv = {};
#pragma unroll
  for (int w2 = 0; w2 < 4; ++w2) {
    float4 a = *(const float4*)(&lds_acc[w2][t * 4]);
    sv.x += fac[w2] * a.x; sv.y += fac[w2] * a.y;
    sv.z += fac[w2] * a.z; sv.w += fac[w2] * a.w;
  }
  const int pc = b * CPB + c;
  *(float4*)(cacc + (size_t)pc * D + t * 4) = sv;
  if (t == 0) { cm[pc] = M; cl[pc] = L; }
}

// ---------------------------------------------------------------------------
// Combine chunk partials. Grid (32 b, 8 dtile) x 128 thr so the 8 MB cacc
// reduction spreads over 256 blocks. Block (b,dt): wm for d in
// [dt*128, dt*128+128) and weight finalization for s in [dt*256, dt*256+256).
__global__ __launch_bounds__(128) void combine(const float* __restrict__ cm,
                                               const float* __restrict__ cl,
                                               const float* __restrict__ cacc,
                                               float* __restrict__ wio,
                                               float* __restrict__ wm) {
  const int b = blockIdx.x, dt = blockIdx.y, t = threadIdx.x;
  float M = -INFINITY;
  for (int c2 = 0; c2 < CPB; ++c2) M = fmaxf(M, cm[b * CPB + c2]);
  __shared__ float fac[CPB];
  if (t < CPB) fac[t] = __expf(cm[b * CPB + t] - M);
  __syncthreads();
  float L = 0.f;
  for (int c2 = 0; c2 < CPB; ++c2) L += cl[b * CPB + c2] * fac[c2];
  const float invL = 1.0f / L;

  const int d = dt * 128 + t;
  float sv = 0.f;
  for (int c2 = 0; c2 < CPB; ++c2)
    sv += fac[c2] * cacc[((size_t)b * CPB + c2) * D + d];
  wm[(size_t)b * D + d] = sv * invL;

  for (int s = dt * 256 + t; s < dt * 256 + 256; s += 128) {
    const float lg = wio[(size_t)b * S + s];
    wio[(size_t)b * S + s] = __expf(lg - M) * invL;
  }
}

// ---------------------------------------------------------------------------
// LayerNorm over last dim per b; out = (h-mu)/sqrt(var+eps)*w + b.
__global__ __launch_bounds__(256) void ln_kernel(const float* __restrict__ h,
                                                 const float* __restrict__ lnw,
                                                 const float* __restrict__ lnb,
                                                 float* __restrict__ out) {
  const int b = blockIdx.x, t = threadIdx.x, wid = t >> 6, lane = t & 63;
  __shared__ float r1[4], r2[4];
  float4 v = *(const float4*)(h + (size_t)b * D + 4 * t);
  float s1 = v.x + v.y + v.z + v.w;
  float s2 = v.x * v.x + v.y * v.y + v.z * v.z + v.w * v.w;
  s1 = wave_sum(s1);
  s2 = wave_sum(s2);
  if (lane == 0) { r1[wid] = s1; r2[wid] = s2; }
  __syncthreads();
  const float mean = (r1[0] + r1[1] + r1[2] + r1[3]) * (1.0f / D);
  const float ms = (r2[0] + r2[1] + r2[2] + r2[3]) * (1.0f / D);
  const float var = ms - mean * mean;
  const float rstd = rsqrtf(var + LN_EPS);
  float4 w = *(const float4*)(lnw + 4 * t);
  float4 bb = *(const float4*)(lnb + 4 * t);
  float4 o;
  o.x = (v.x - mean) * rstd * w.x + bb.x;
  o.y = (v.y - mean) * rstd * w.y + bb.y;
  o.z = (v.z - mean) * rstd * w.z + bb.z;
  o.w = (v.w - mean) * rstd * w.w + bb.w;
  *(float4*)(out + (size_t)b * D + 4 * t) = o;
}

// ---------------------------------------------------------------------------
extern "C" void kernel_launch(void* const* d_in, const int* in_sizes, int n_in,
                              void* d_out, int out_size, void* d_ws,
                              size_t ws_size, hipStream_t stream) {
  (void)in_sizes; (void)n_in; (void)out_size; (void)ws_size;
  const float* meta   = (const float*)d_in[0];
  const float* hidden = (const float*)d_in[1];
  const float* WK = (const float*)d_in[2];
  const float* WQ = (const float*)d_in[3];
  const float* WV = (const float*)d_in[4];
  const float* WO = (const float*)d_in[5];
  const float* lnw = (const float*)d_in[6];
  const float* lnb = (const float*)d_in[7];

  float* out  = (float*)d_out;        // [B, D] LayerNorm output
  float* wout = out + B * D;          // [B, S] softmax weights (logits first)

  // workspace layout (floats); total ~2.8M floats ~= 11 MB
  float* ws   = (float*)d_ws;
  float* q    = ws;                         // B*D
  float* kqp  = q + B * D;                  // ACH*B*D
  float* cm   = kqp + (size_t)ACH * B * D;  // B*CPB
  float* cl   = cm + B * CPB;               // B*CPB
  float* cacc = cl + B * CPB;               // B*CPB*D
  float* wm   = cacc + (size_t)B * CPB * D; // B*D
  float* att  = wm + B * D;                 // B*D
  float* h    = att + B * D;                // B*D

  // q = hidden @ WQ^T
  gemm_xw<<<dim3(8, 32), 256, 0, stream>>>(hidden, WQ, q, 0);
  // kq partials = q @ WK (reduction over chunks fused into attn_main)
  kq_partial<<<dim3(ACH, 4), 256, 0, stream>>>(q, WK, kqp);
  // single pass over meta: logits + online-softmax weighted-meta partials
  attn_main<<<dim3(CPB, B), 256, 0, stream>>>(meta, kqp, wout, cm, cl, cacc);
  // combine partials -> wm, finalize weights in d_out
  combine<<<dim3(B, 8), 128, 0, stream>>>(cm, cl, cacc, wout, wm);
  // attention = wm @ WV^T ; h = tanh(attention @ WO^T) ; out = LN(h)
  gemm_xw<<<dim3(8, 32), 256, 0, stream>>>(wm, WV, att, 0);
  gemm_xw<<<dim3(8, 32), 256, 0, stream>>>(att, WO, h, 1);
  ln_kernel<<<dim3(B), 256, 0, stream>>>(h, lnw, lnb, out);
}